// Round 5
// baseline (53.628 us; speedup 1.0000x reference)
//
#include <hip/hip_runtime.h>
#include <hip/hip_cooperative_groups.h>

namespace cg = cooperative_groups;

#define BB 128
#define TT 512
#define LAG_PENALTY 0.5f

// ---- cooperative fused version: 512 blocks x 512 thr = 2 blocks/CU ----
#define CSPLIT 4          // lag-chunks per row
#define CCHUNK 128        // lags per chunk (4*128 = 512 >= 511)
#define CNB (BB * CSPLIT) // 512 blocks

__global__ __launch_bounds__(512, 4) void WeightedLagDenseLoss_fused(
    const float* __restrict__ pred,
    const float* __restrict__ tgt,
    const float* __restrict__ wts,
    float* __restrict__ part,     // d_ws, CNB floats
    float* __restrict__ out)
{
    __shared__ float s_tgt[TT];
    __shared__ float s_rinv[TT];
    __shared__ float s_part[8];

    const int bid = blockIdx.x;
    const int b = bid >> 2;       // row
    const int s = bid & 3;        // lag chunk
    const int t = threadIdx.x;

    s_tgt[t]  = tgt[b * TT + t];
    s_rinv[t] = (t >= 1) ? (1.0f / (float)t) : 0.0f;
    __syncthreads();

    const float p = pred[b * TT + t];

    const int l0 = 1 + s * CCHUNK;
    const int l1 = min(TT, l0 + CCHUNK);   // s=3: 385..511 (127 lags)

    float acc0 = 0.0f, acc1 = 0.0f;
    #pragma unroll 8
    for (int l = l0; l + 1 < l1; l += 2) {
        int   i0 = min(t + l, TT - 1);
        float d0 = p - s_tgt[i0];
        acc0 = fmaf(s_rinv[l] * d0, d0, acc0);
        int   i1 = min(t + l + 1, TT - 1);
        float d1 = p - s_tgt[i1];
        acc1 = fmaf(s_rinv[l + 1] * d1, d1, acc1);
    }
    if (((l1 - l0) & 1) != 0) {
        int   l = l1 - 1;
        int   i = min(t + l, TT - 1);
        float d = p - s_tgt[i];
        acc0 = fmaf(s_rinv[l] * d, d, acc0);
    }
    float tot = LAG_PENALTY * (acc0 + acc1);

    if (s == CSPLIT - 1) {        // plain MSE term exactly once
        float dm = p - s_tgt[t];
        tot = fmaf(dm, dm, tot);
    }

    float v = tot * wts[b] * (1.0f / (float)(BB * TT));

    for (int off = 32; off > 0; off >>= 1)
        v += __shfl_down(v, off, 64);

    const int wave = t >> 6;
    if ((t & 63) == 0) s_part[wave] = v;
    __syncthreads();

    if (t == 0) {
        float sum = 0.0f;
        #pragma unroll
        for (int i = 0; i < 8; ++i) sum += s_part[i];
        part[bid] = sum;
    }

    cg::this_grid().sync();

    if (bid == 0) {               // final reduce: 512 partials, 1/thread
        float r = part[t];
        for (int off = 32; off > 0; off >>= 1)
            r += __shfl_down(r, off, 64);
        if ((t & 63) == 0) s_part[t >> 6] = r;
        __syncthreads();
        if (t == 0) {
            float sum = 0.0f;
            #pragma unroll
            for (int i = 0; i < 8; ++i) sum += s_part[i];
            out[0] = sum;
        }
    }
}

// ---- fallback: proven R3 two-kernel path (13.7 us) ----
#define SPLIT 8
#define CHUNK 64
#define NPART (BB * SPLIT)

__global__ __launch_bounds__(512) void WeightedLagDenseLoss_partial(
    const float* __restrict__ pred,
    const float* __restrict__ tgt,
    const float* __restrict__ wts,
    float* __restrict__ part)
{
    __shared__ float s_tgt[TT];
    __shared__ float s_rinv[TT];
    __shared__ float s_part[8];

    const int b = blockIdx.x;
    const int s = blockIdx.y;
    const int t = threadIdx.x;

    s_tgt[t]  = tgt[b * TT + t];
    s_rinv[t] = (t >= 1) ? (1.0f / (float)t) : 0.0f;
    __syncthreads();

    const float p = pred[b * TT + t];

    const int l0 = 1 + s * CHUNK;
    const int l1 = min(TT, l0 + CHUNK);

    float acc0 = 0.0f, acc1 = 0.0f;
    #pragma unroll 8
    for (int l = l0; l + 1 < l1; l += 2) {
        int   i0 = min(t + l, TT - 1);
        float d0 = p - s_tgt[i0];
        acc0 = fmaf(s_rinv[l] * d0, d0, acc0);
        int   i1 = min(t + l + 1, TT - 1);
        float d1 = p - s_tgt[i1];
        acc1 = fmaf(s_rinv[l + 1] * d1, d1, acc1);
    }
    if (((l1 - l0) & 1) != 0) {
        int   l = l1 - 1;
        int   i = min(t + l, TT - 1);
        float d = p - s_tgt[i];
        acc0 = fmaf(s_rinv[l] * d, d, acc0);
    }
    float tot = LAG_PENALTY * (acc0 + acc1);

    if (s == SPLIT - 1) {
        float dm = p - s_tgt[t];
        tot = fmaf(dm, dm, tot);
    }

    float v = tot * wts[b] * (1.0f / (float)(BB * TT));

    for (int off = 32; off > 0; off >>= 1)
        v += __shfl_down(v, off, 64);

    const int wave = t >> 6;
    if ((t & 63) == 0) s_part[wave] = v;
    __syncthreads();

    if (t == 0) {
        float sum = 0.0f;
        #pragma unroll
        for (int i = 0; i < 8; ++i) sum += s_part[i];
        part[b * SPLIT + s] = sum;
    }
}

__global__ __launch_bounds__(1024) void WeightedLagDenseLoss_reduce(
    const float* __restrict__ part,
    float* __restrict__ out)
{
    __shared__ float s_part[16];
    const int t = threadIdx.x;

    float v = part[t];

    for (int off = 32; off > 0; off >>= 1)
        v += __shfl_down(v, off, 64);

    const int wave = t >> 6;
    if ((t & 63) == 0) s_part[wave] = v;
    __syncthreads();

    if (t == 0) {
        float sum = 0.0f;
        #pragma unroll
        for (int i = 0; i < 16; ++i) sum += s_part[i];
        out[0] = sum;
    }
}

extern "C" void kernel_launch(void* const* d_in, const int* in_sizes, int n_in,
                              void* d_out, int out_size, void* d_ws, size_t ws_size,
                              hipStream_t stream) {
    const float* pred = (const float*)d_in[0];
    const float* tgt  = (const float*)d_in[1];
    const float* wts  = (const float*)d_in[2];
    float* out  = (float*)d_out;
    float* part = (float*)d_ws;

    void* args[] = { (void*)&pred, (void*)&tgt, (void*)&wts,
                     (void*)&part, (void*)&out };
    hipError_t err = hipLaunchCooperativeKernel(
        (void*)WeightedLagDenseLoss_fused,
        dim3(CNB), dim3(TT), args, 0, stream);

    if (err != hipSuccess) {
        // Deterministic fallback: same config -> same branch every call.
        WeightedLagDenseLoss_partial<<<dim3(BB, SPLIT), dim3(TT), 0, stream>>>(pred, tgt, wts, part);
        WeightedLagDenseLoss_reduce<<<dim3(1), dim3(NPART), 0, stream>>>(part, out);
    }
}

// Round 6
// 25.379 us; speedup vs baseline: 2.1131x; 2.1131x over previous
//
#include <hip/hip_runtime.h>

#define BB 128
#define TT 512
#define LAG_PENALTY 0.5f

// Grid: 1024 blocks = 128 rows x 8 lag-chunks (64 lags each).
// Block: 512 threads = 128 t-groups (4 consecutive t) x 4 lag-subchunks (16 lags).
// Per thread: 4 lag-groups of 4; each group = 2 aligned ds_read_b128 (8-float
// window) covering the 4x4 (t,l) tile. Lag 0 included with weight 0 so the
// lag axis starts at a multiple of 4.

__global__ __launch_bounds__(1, 1) void WeightedLagDenseLoss_zero(float* out) {
    out[0] = 0.0f;
}

__global__ __launch_bounds__(512, 4) void WeightedLagDenseLoss_main(
    const float* __restrict__ pred,
    const float* __restrict__ tgt,
    const float* __restrict__ wts,
    float* __restrict__ out)
{
    __shared__ float4 s_ext4[256];   // 1024 floats: row [0..511], g511 [512..1023]
    __shared__ float  s_part[8];
    float* s_ext = reinterpret_cast<float*>(s_ext4);

    const int bid = blockIdx.x;
    const int row = bid >> 3;        // 0..127
    const int s   = bid & 7;         // lag chunk: lags [64s, 64s+64)
    const int tid = threadIdx.x;
    const int j   = tid & 127;       // t-group: t = 4j..4j+3
    const int q   = tid >> 7;        // lag subchunk: lags [64s+16q, +16)

    // Stage extended target row: [0..511] = row, [512..1023] = g[511] (clamp pad)
    const float g511 = tgt[row * TT + TT - 1];   // uniform address, broadcast
    s_ext[tid]       = tgt[row * TT + tid];
    s_ext[TT + tid]  = g511;
    __syncthreads();

    // 1/l table for this thread's 16 lags (l = L0 + i), via v_rcp (off LDS pipe)
    const int L0 = 64 * s + 16 * q;
    float r[16];
    #pragma unroll
    for (int i = 0; i < 16; ++i) {
        const int l = L0 + i;
        r[i] = (l == 0) ? 0.0f : __builtin_amdgcn_rcpf((float)l);
    }

    const float4 p = *reinterpret_cast<const float4*>(&pred[row * TT + 4 * j]);

    float acc = 0.0f;     // sum over 16 lags x 4 t of (1/l) * d^2
    float mse = 0.0f;     // plain MSE for this thread's 4 t's (added once)
    const bool own_mse = (s == 0) && (q == 0);   // lag-group l=0 block

    #pragma unroll
    for (int k = 0; k < 4; ++k) {
        const int base4 = j + (L0 >> 2) + k;     // float4 index, exact
        const float4 w0 = s_ext4[base4];
        const float4 w1 = s_ext4[base4 + 1];
        const float gg[7] = { w0.x, w0.y, w0.z, w0.w, w1.x, w1.y, w1.z };

        #pragma unroll
        for (int bb = 0; bb < 4; ++bb) {
            const float d0 = p.x - gg[bb + 0];
            const float d1 = p.y - gg[bb + 1];
            const float d2 = p.z - gg[bb + 2];
            const float d3 = p.w - gg[bb + 3];
            const float sb = d0 * d0 + d1 * d1 + d2 * d2 + d3 * d3;
            acc = fmaf(r[4 * k + bb], sb, acc);
            if (k == 0 && bb == 0 && own_mse) mse = sb;   // l=0 tile IS the MSE
        }
    }

    // total = (mse + 0.5*lag) * w, mean scale 1/(B*T) = 1/65536 exact
    float v = fmaf(LAG_PENALTY, acc, mse) * wts[row] * (1.0f / (float)(BB * TT));

    // wave64 shuffle reduction -> per-block sum -> one atomic per block
    for (int off = 32; off > 0; off >>= 1)
        v += __shfl_down(v, off, 64);

    const int wave = tid >> 6;
    if ((tid & 63) == 0) s_part[wave] = v;
    __syncthreads();

    if (tid == 0) {
        float sum = 0.0f;
        #pragma unroll
        for (int i = 0; i < 8; ++i) sum += s_part[i];
        atomicAdd(out, sum);
    }
}

extern "C" void kernel_launch(void* const* d_in, const int* in_sizes, int n_in,
                              void* d_out, int out_size, void* d_ws, size_t ws_size,
                              hipStream_t stream) {
    const float* pred = (const float*)d_in[0];
    const float* tgt  = (const float*)d_in[1];
    const float* wts  = (const float*)d_in[2];
    float* out = (float*)d_out;

    WeightedLagDenseLoss_zero<<<dim3(1), dim3(1), 0, stream>>>(out);
    WeightedLagDenseLoss_main<<<dim3(BB * 8), dim3(TT), 0, stream>>>(pred, tgt, wts, out);
}

// Round 7
// 11.498 us; speedup vs baseline: 4.6642x; 2.2073x over previous
//
#include <hip/hip_runtime.h>

#define BB 128
#define TT 512
#define NPART (BB * 8)   // 1024 partials
#define LAG_PENALTY 0.5f

// Grid: 1024 blocks = 128 rows x 8 lag-chunks (64 lags each).
// Block: 512 threads = 128 t-groups (4 consecutive t) x 4 lag-subchunks (16 lags).
// Per thread: sliding 20-float window = 5 aligned ds_read_b128 covering all
// 4 lag-groups (consecutive groups share window halves). Lag 0 carried at
// weight rinv[0]=0; its diff^2 tile IS the MSE term (added once by s=0,q=0).

__global__ __launch_bounds__(512, 4) void WeightedLagDenseLoss_main(
    const float* __restrict__ pred,
    const float* __restrict__ tgt,
    const float* __restrict__ wts,
    float* __restrict__ part)
{
    __shared__ float4 s_ext4[256];   // 1024 floats: row [0..511], g511-pad [512..1023]
    __shared__ float  s_part[8];
    float* s_ext = reinterpret_cast<float*>(s_ext4);

    const int bid = blockIdx.x;
    const int row = bid >> 3;        // 0..127
    const int s   = bid & 7;         // lag chunk: lags [64s, 64s+64)
    const int tid = threadIdx.x;
    const int j   = tid & 127;       // t-group: t = 4j..4j+3
    const int q   = tid >> 7;        // lag subchunk: lags [64s+16q, +16)

    // Stage extended target row: [0..511] = row, [512..1023] = g[511] (clamp pad)
    const float g511 = tgt[row * TT + TT - 1];   // uniform address, broadcast
    s_ext[tid]       = tgt[row * TT + tid];
    s_ext[TT + tid]  = g511;
    __syncthreads();

    // 1/l for this thread's 16 lags (l = L0 + i), v_rcp (off the LDS pipe)
    const int L0 = 64 * s + 16 * q;
    float r[16];
    #pragma unroll
    for (int i = 0; i < 16; ++i) {
        const int l = L0 + i;
        r[i] = (l == 0) ? 0.0f : __builtin_amdgcn_rcpf((float)l);
    }

    const float4 p = *reinterpret_cast<const float4*>(&pred[row * TT + 4 * j]);

    // 20-float window: float4 indices base4 .. base4+4 (max 255, exact fit)
    const int base4 = j + (L0 >> 2);
    float4 w4[5];
    #pragma unroll
    for (int k = 0; k < 5; ++k) w4[k] = s_ext4[base4 + k];
    const float* w = reinterpret_cast<const float*>(w4);

    float acc = 0.0f;     // sum over 16 lags x 4 t of (1/l) * d^2
    float mse = 0.0f;     // plain MSE for this thread's 4 t's
    const bool own_mse = (s == 0) && (q == 0);

    #pragma unroll
    for (int k = 0; k < 4; ++k) {
        #pragma unroll
        for (int bb = 0; bb < 4; ++bb) {
            const int o = 4 * k + bb;
            const float d0 = p.x - w[o + 0];
            const float d1 = p.y - w[o + 1];
            const float d2 = p.z - w[o + 2];
            const float d3 = p.w - w[o + 3];
            const float sb = d0 * d0 + d1 * d1 + d2 * d2 + d3 * d3;
            acc = fmaf(r[o], sb, acc);
            if (k == 0 && bb == 0 && own_mse) mse = sb;   // l=0 tile IS the MSE
        }
    }

    // total = (mse + 0.5*lag) * w, mean scale 1/(B*T) = 1/65536 exact
    float v = fmaf(LAG_PENALTY, acc, mse) * wts[row] * (1.0f / (float)(BB * TT));

    // wave64 shuffle reduction -> per-block partial (plain store, no atomic)
    for (int off = 32; off > 0; off >>= 1)
        v += __shfl_down(v, off, 64);

    const int wave = tid >> 6;
    if ((tid & 63) == 0) s_part[wave] = v;
    __syncthreads();

    if (tid == 0) {
        float sum = 0.0f;
        #pragma unroll
        for (int i = 0; i < 8; ++i) sum += s_part[i];
        part[bid] = sum;             // overwritten every call
    }
}

__global__ __launch_bounds__(1024) void WeightedLagDenseLoss_reduce(
    const float* __restrict__ part,
    float* __restrict__ out)
{
    __shared__ float s_part[16];
    const int t = threadIdx.x;

    float v = part[t];               // NPART == 1024 == blockDim.x

    for (int off = 32; off > 0; off >>= 1)
        v += __shfl_down(v, off, 64);

    const int wave = t >> 6;
    if ((t & 63) == 0) s_part[wave] = v;
    __syncthreads();

    if (t == 0) {
        float sum = 0.0f;
        #pragma unroll
        for (int i = 0; i < 16; ++i) sum += s_part[i];
        out[0] = sum;                // overwrite, no zero-init needed
    }
}

extern "C" void kernel_launch(void* const* d_in, const int* in_sizes, int n_in,
                              void* d_out, int out_size, void* d_ws, size_t ws_size,
                              hipStream_t stream) {
    const float* pred = (const float*)d_in[0];
    const float* tgt  = (const float*)d_in[1];
    const float* wts  = (const float*)d_in[2];
    float* out  = (float*)d_out;
    float* part = (float*)d_ws;      // 1024 floats = 4 KB scratch

    WeightedLagDenseLoss_main<<<dim3(NPART), dim3(TT), 0, stream>>>(pred, tgt, wts, part);
    WeightedLagDenseLoss_reduce<<<dim3(1), dim3(NPART), 0, stream>>>(part, out);
}